// Round 6
// baseline (1284.563 us; speedup 1.0000x reference)
//
#include <hip/hip_runtime.h>
#include <hip/hip_bf16.h>
#include <stdint.h>

typedef __attribute__((ext_vector_type(8))) short bf16x8;
typedef __attribute__((ext_vector_type(4))) float f32x4;

__device__ __forceinline__ unsigned short f32_to_bf16_rtn(float x) {
    unsigned u = __float_as_uint(x);
    u += 0x7FFFu + ((u >> 16) & 1u);
    return (unsigned short)(u >> 16);
}
__device__ __forceinline__ float bf16_bits_to_f32(unsigned short h) {
    return __uint_as_float(((unsigned)h) << 16);
}

// ---------------------------------------------------------------------------
// Kernel 1: split fp32 inputs into hi/lo bf16 pairs (a = hi + lo, err ~2^-17)
// ---------------------------------------------------------------------------
__global__ __launch_bounds__(256) void split_hi_lo(
    const float* __restrict__ A, const float* __restrict__ B,
    unsigned short* __restrict__ Ahi, unsigned short* __restrict__ Alo,
    unsigned short* __restrict__ Bhi, unsigned short* __restrict__ Blo, int n4)
{
    int i = blockIdx.x * 256 + threadIdx.x;
    if (i >= n4) return;
    float4 a = ((const float4*)A)[i];
    float4 b = ((const float4*)B)[i];
    ushort4 h, l;

    h.x = f32_to_bf16_rtn(a.x); l.x = f32_to_bf16_rtn(a.x - bf16_bits_to_f32(h.x));
    h.y = f32_to_bf16_rtn(a.y); l.y = f32_to_bf16_rtn(a.y - bf16_bits_to_f32(h.y));
    h.z = f32_to_bf16_rtn(a.z); l.z = f32_to_bf16_rtn(a.z - bf16_bits_to_f32(h.z));
    h.w = f32_to_bf16_rtn(a.w); l.w = f32_to_bf16_rtn(a.w - bf16_bits_to_f32(h.w));
    ((ushort4*)Ahi)[i] = h; ((ushort4*)Alo)[i] = l;

    h.x = f32_to_bf16_rtn(b.x); l.x = f32_to_bf16_rtn(b.x - bf16_bits_to_f32(h.x));
    h.y = f32_to_bf16_rtn(b.y); l.y = f32_to_bf16_rtn(b.y - bf16_bits_to_f32(h.y));
    h.z = f32_to_bf16_rtn(b.z); l.z = f32_to_bf16_rtn(b.z - bf16_bits_to_f32(h.z));
    h.w = f32_to_bf16_rtn(b.w); l.w = f32_to_bf16_rtn(b.w - bf16_bits_to_f32(h.w));
    ((ushort4*)Bhi)[i] = h; ((ushort4*)Blo)[i] = l;
}

// ---------------------------------------------------------------------------
// Kernel 2 (presplit, hot path): energies = A @ B^T, split-bf16 3-product GEMM.
// BARRIER-FREE flatmm-style: no LDS, fragments loaded directly global->VGPR
// with a 1-iteration register double buffer. Rationale (r5 counters): with
// LDS staging, MfmaUtil 53% / VALUBusy 44% / conflicts 0 and dur stuck at
// ~385 us = the m97 barrier-drain plateau (compiler emits vmcnt(0) before
// every s_barrier). Removing barriers lets the compiler emit partial vmcnt
// waits so prefetched loads stay in flight across compute. Inputs (67 MB)
// are L3-resident; intra-block 2x fragment reuse is L1's job.
// 128x128 block tile, BK=32, 4 waves (2x2), each wave 64x64 = 4x4 MFMA tiles.
// ---------------------------------------------------------------------------
__global__ __launch_bounds__(256) void gemm_direct(
    const unsigned short* __restrict__ Ahi, const unsigned short* __restrict__ Alo,
    const unsigned short* __restrict__ Bhi, const unsigned short* __restrict__ Blo,
    float* __restrict__ out, int M, int N, int K)
{
    const int tid  = threadIdx.x;
    const int lane = tid & 63;
    const int w    = tid >> 6;
    const int bm = blockIdx.y, bn = blockIdx.x;
    const int wm = (w >> 1) * 64;
    const int wn = (w & 1) * 64;

    f32x4 acc[4][4] = {};

    // Fragment addressing (same m<->lane&15, kchunk<->lane>>4 mapping that
    // r1-r5 fed MFMA via LDS; here straight from global).
    const int rA = lane & 15;
    const int kc = (lane >> 4) << 3;   // k element offset 0/8/16/24
    int aoff[4], boff[4];              // element offsets, fit in int (<16.8M)
#pragma unroll
    for (int i = 0; i < 4; ++i) {
        aoff[i] = (bm * 128 + wm + i * 16 + rA) * K + kc;
        boff[i] = (bn * 128 + wn + i * 16 + rA) * K + kc;
    }

    bf16x8 ah[2][4], al[2][4], bh[2][4], bl[2][4];

#define LOADF(buf, kk)                                                        \
    {                                                                         \
        _Pragma("unroll")                                                     \
        for (int i = 0; i < 4; ++i) {                                         \
            ah[buf][i] = *(const bf16x8*)(Ahi + aoff[i] + (kk));              \
            al[buf][i] = *(const bf16x8*)(Alo + aoff[i] + (kk));              \
            bh[buf][i] = *(const bf16x8*)(Bhi + boff[i] + (kk));              \
            bl[buf][i] = *(const bf16x8*)(Blo + boff[i] + (kk));              \
        }                                                                     \
    }

#define MFMAS(buf)                                                            \
    {                                                                         \
        _Pragma("unroll")                                                     \
        for (int i = 0; i < 4; ++i) {                                         \
            _Pragma("unroll")                                                 \
            for (int j = 0; j < 4; ++j) {                                     \
                acc[i][j] = __builtin_amdgcn_mfma_f32_16x16x32_bf16(          \
                    ah[buf][i], bh[buf][j], acc[i][j], 0, 0, 0);              \
                acc[i][j] = __builtin_amdgcn_mfma_f32_16x16x32_bf16(          \
                    al[buf][i], bh[buf][j], acc[i][j], 0, 0, 0);              \
                acc[i][j] = __builtin_amdgcn_mfma_f32_16x16x32_bf16(          \
                    ah[buf][i], bl[buf][j], acc[i][j], 0, 0, 0);              \
            }                                                                 \
        }                                                                     \
    }

    LOADF(0, 0);
    for (int k0 = 0; k0 < K; k0 += 64) {
        LOADF(1, k0 + 32);          // prefetch while buf0 in flight/consumed
        MFMAS(0);
        if (k0 + 64 < K) LOADF(0, k0 + 64);
        MFMAS(1);
    }
#undef LOADF
#undef MFMAS

    // Epilogue: 16x16 C/D layout col=lane&15, row=(lane>>4)*4+reg (m89/m91)
    const int r0 = bm * 128 + wm + ((lane >> 4) << 2);
    const int c0 = bn * 128 + wn + rA;
#pragma unroll
    for (int i = 0; i < 4; ++i)
#pragma unroll
        for (int j = 0; j < 4; ++j)
#pragma unroll
            for (int r = 0; r < 4; ++r)
                out[(size_t)(r0 + i * 16 + r) * N + (c0 + j * 16)] = acc[i][j][r];
}

// ---------------------------------------------------------------------------
// Kernel 2b (fallback, ws too small — not expected to run): inline split, LDS.
// ---------------------------------------------------------------------------
__global__ __launch_bounds__(256) void gemm_fallback(
    const float* __restrict__ Af, const float* __restrict__ Bf,
    float* __restrict__ out, int M, int N, int K)
{
    __shared__ char sm[32768];
    const int tid  = threadIdx.x;
    const int lane = tid & 63;
    const int w    = tid >> 6;
    const int bm = blockIdx.y, bn = blockIdx.x;
    const int wm = (w >> 1) * 64;
    const int wn = (w & 1) * 64;

    f32x4 acc[4][4] = {};
    const int sfetch = (tid & 3) ^ ((tid >> 3) & 3);
    const int rA = lane & 15;
    const int ca = (lane >> 4) ^ ((lane >> 1) & 3);
    const char* aP = sm +         (wm + rA) * 64 + ca * 16;
    const char* bP = sm + 16384 + (wn + rA) * 64 + ca * 16;

    for (int k0 = 0; k0 < K; k0 += 32) {
        __syncthreads();
#pragma unroll
        for (int c = 0; c < 4; ++c) {
            const bool isA = (c < 2);
            const int row = ((c & 1) << 6) + (tid >> 2);
            const float* src = (isA ? Af + (size_t)(bm * 128 + row) * K
                                    : Bf + (size_t)(bn * 128 + row) * K)
                               + k0 + ((tid & 3) << 3);
            f32x4 v0 = *(const f32x4*)src;
            f32x4 v1 = *(const f32x4*)(src + 4);
            float vv[8] = {v0.x, v0.y, v0.z, v0.w, v1.x, v1.y, v1.z, v1.w};
            bf16x8 h, l;
#pragma unroll
            for (int j = 0; j < 8; ++j) {
                unsigned short hb = f32_to_bf16_rtn(vv[j]);
                unsigned short lb = f32_to_bf16_rtn(vv[j] - bf16_bits_to_f32(hb));
                h[j] = (short)hb; l[j] = (short)lb;
            }
            const int g = row * 64 + sfetch * 16;
            *(bf16x8*)(sm + (isA ? 0 : 16384) + g) = h;
            *(bf16x8*)(sm + (isA ? 8192 : 24576) + g) = l;
        }
        __syncthreads();

        bf16x8 bh[4], bl[4];
#pragma unroll
        for (int j = 0; j < 4; ++j) {
            bh[j] = *(const bf16x8*)(bP + j * 1024);
            bl[j] = *(const bf16x8*)(bP + j * 1024 + 8192);
        }
#pragma unroll
        for (int i = 0; i < 4; ++i) {
            bf16x8 ah = *(const bf16x8*)(aP + i * 1024);
            bf16x8 al = *(const bf16x8*)(aP + i * 1024 + 8192);
#pragma unroll
            for (int j = 0; j < 4; ++j) {
                acc[i][j] = __builtin_amdgcn_mfma_f32_16x16x32_bf16(ah, bh[j], acc[i][j], 0, 0, 0);
                acc[i][j] = __builtin_amdgcn_mfma_f32_16x16x32_bf16(al, bh[j], acc[i][j], 0, 0, 0);
                acc[i][j] = __builtin_amdgcn_mfma_f32_16x16x32_bf16(ah, bl[j], acc[i][j], 0, 0, 0);
            }
        }
    }

    const int r0 = bm * 128 + wm + ((lane >> 4) << 2);
    const int c0 = bn * 128 + wn + rA;
#pragma unroll
    for (int i = 0; i < 4; ++i)
#pragma unroll
        for (int j = 0; j < 4; ++j)
#pragma unroll
            for (int r = 0; r < 4; ++r)
                out[(size_t)(r0 + i * 16 + r) * N + (c0 + j * 16)] = acc[i][j][r];
}

// ---------------------------------------------------------------------------
// Kernel 3: in-place row softmax, persistent blocks (r5 version, neutral).
// 2048 blocks x 256 threads; each block does 4 rows of 8192 floats.
// ---------------------------------------------------------------------------
__global__ __launch_bounds__(256) void softmax_rows_8192(float* __restrict__ d)
{
    const int tid = threadIdx.x;
    __shared__ float smax[4], ssum[4];

    for (int rr = 0; rr < 4; ++rr) {
        const size_t row = (size_t)blockIdx.x * 4 + rr;
        f32x4* p = (f32x4*)(d + row * 8192);
        f32x4 v[8];
        float m = -3.402823466e+38f;
#pragma unroll
        for (int i = 0; i < 8; ++i) {
            v[i] = p[tid + (i << 8)];
            m = fmaxf(m, fmaxf(fmaxf(v[i].x, v[i].y), fmaxf(v[i].z, v[i].w)));
        }
#pragma unroll
        for (int o = 32; o >= 1; o >>= 1) m = fmaxf(m, __shfl_xor(m, o));
        if ((tid & 63) == 0) smax[tid >> 6] = m;
        __syncthreads();
        m = fmaxf(fmaxf(smax[0], smax[1]), fmaxf(smax[2], smax[3]));

        float s = 0.f;
#pragma unroll
        for (int i = 0; i < 8; ++i) {
            v[i].x = __expf(v[i].x - m);
            v[i].y = __expf(v[i].y - m);
            v[i].z = __expf(v[i].z - m);
            v[i].w = __expf(v[i].w - m);
            s += (v[i].x + v[i].y) + (v[i].z + v[i].w);
        }
#pragma unroll
        for (int o = 32; o >= 1; o >>= 1) s += __shfl_xor(s, o);
        if ((tid & 63) == 0) ssum[tid >> 6] = s;
        __syncthreads();
        s = (ssum[0] + ssum[1]) + (ssum[2] + ssum[3]);
        const float r = 1.0f / s;
#pragma unroll
        for (int i = 0; i < 8; ++i) {
            v[i] *= r;
            __builtin_nontemporal_store(v[i], &p[tid + (i << 8)]);
        }
        __syncthreads();   // smax/ssum reused next row
    }
}

// ---------------------------------------------------------------------------
extern "C" void kernel_launch(void* const* d_in, const int* in_sizes, int n_in,
                              void* d_out, int out_size, void* d_ws, size_t ws_size,
                              hipStream_t stream)
{
    const float* A = (const float*)d_in[0];   // user_emb [M, K] fp32
    const float* B = (const float*)d_in[1];   // id_emb   [N, K] fp32
    float* out = (float*)d_out;               // [M, N] fp32
    const int K = 1024;
    const int M = in_sizes[0] / K;
    const int N = in_sizes[1] / K;
    const size_t elemsA = (size_t)M * K;
    const size_t elemsB = (size_t)N * K;
    const size_t need = 2 * (elemsA + elemsB) * sizeof(unsigned short);

    dim3 grid(N / 128, M / 128);
    const bool presplit = (ws_size >= need) && (M == N);

    if (presplit) {
        unsigned short* Ahi = (unsigned short*)d_ws;
        unsigned short* Alo = Ahi + elemsA;
        unsigned short* Bhi = Alo + elemsA;
        unsigned short* Blo = Bhi + elemsB;
        const int n4 = (int)(elemsA / 4);
        split_hi_lo<<<(n4 + 255) / 256, 256, 0, stream>>>(A, B, Ahi, Alo, Bhi, Blo, n4);
        gemm_direct<<<grid, 256, 0, stream>>>(Ahi, Alo, Bhi, Blo, out, M, N, K);
    } else {
        gemm_fallback<<<grid, 256, 0, stream>>>(A, B, out, M, N, K);
    }
    softmax_rows_8192<<<M / 4, 256, 0, stream>>>(out);
}